// Round 4
// baseline (14491.377 us; speedup 1.0000x reference)
//
#include <hip/hip_runtime.h>
#include <hip/hip_bf16.h>

// ---------------------------------------------------------------------------
// UFGConv: out = sum_b A_b * (filter_b . (A_b * (x @ W)))
// N=100000, F=128, E=3.2M per branch (3 branches).
// R4: eliminate per-row CSR (100K-cursor scatter had 8x write amplification).
//     Hierarchical bucketing: 196 coarse (512-row) -> 8 fine (64-row) each,
//     block-aggregated scatter (contiguous runs -> full-line writes),
//     SPMM with 64x128 fp32 LDS accumulator per fine bucket.
// ---------------------------------------------------------------------------

#define CHUNK 8192     // edges per scatter/hist block
#define CITER 32       // CHUNK / 256
#define MAXC 256       // max coarse buckets (N <= 131072)

static __device__ __forceinline__ unsigned short bf16bits(float v) {
  return __builtin_bit_cast(unsigned short, __float2bfloat16(v));
}

__global__ __launch_bounds__(256) void gemm128(const float* __restrict__ x,
                                               const float* __restrict__ w,
                                               unsigned short* __restrict__ y,
                                               int n) {
  __shared__ float4 wsh[128][32];
  __shared__ float xsh[8][128];
  const int tid = threadIdx.x;
  for (int i = tid; i < 128 * 32; i += 256)
    wsh[i >> 5][i & 31] = ((const float4*)w)[i];
  const int rowbase = blockIdx.x * 8;
  for (int i = tid; i < 8 * 128; i += 256) {
    int r = rowbase + (i >> 7);
    xsh[i >> 7][i & 127] = (r < n) ? x[(size_t)r * 128 + (i & 127)] : 0.f;
  }
  __syncthreads();
  const int r = tid >> 5, cg = tid & 31;
  float4 acc = {0.f, 0.f, 0.f, 0.f};
#pragma unroll
  for (int k = 0; k < 128; ++k) {
    float xv = xsh[r][k];
    float4 wv = wsh[k][cg];
    acc.x += xv * wv.x;
    acc.y += xv * wv.y;
    acc.z += xv * wv.z;
    acc.w += xv * wv.w;
  }
  if (rowbase + r < n) {
    ushort4 o;
    o.x = bf16bits(acc.x);
    o.y = bf16bits(acc.y);
    o.z = bf16bits(acc.z);
    o.w = bf16bits(acc.w);
    ((ushort4*)y)[(size_t)(rowbase + r) * 32 + cg] = o;
  }
}

// Coarse histogram: bucket = row >> 9, LDS-aggregated.
__global__ __launch_bounds__(256) void bhist(const int* __restrict__ rows,
                                             int* __restrict__ bcnt, int E,
                                             int NC) {
  __shared__ int h[MAXC];
  const int tid = threadIdx.x;
  h[tid] = 0;
  __syncthreads();
  const int base = blockIdx.x * CHUNK;
  for (int k = 0; k < CITER; ++k) {
    int e = base + k * 256 + tid;
    if (e < E) atomicAdd(&h[rows[e] >> 9], 1);
  }
  __syncthreads();
  if (tid < NC && h[tid]) atomicAdd(&bcnt[tid], h[tid]);
}

// Exclusive scan over NC coarse counts (NC <= 256); init cursors + sentinel.
__global__ __launch_bounds__(256) void bscan(const int* __restrict__ bcnt,
                                             int* __restrict__ cstart,
                                             int* __restrict__ gcur,
                                             int* __restrict__ fptr, int NC,
                                             int NFB) {
  __shared__ int sh[256];
  const int tid = threadIdx.x;
  int v = (tid < NC) ? bcnt[tid] : 0;
  sh[tid] = v;
  __syncthreads();
  for (int o = 1; o < 256; o <<= 1) {
    int t2 = (tid >= o) ? sh[tid - o] : 0;
    __syncthreads();
    sh[tid] += t2;
    __syncthreads();
  }
  if (tid < NC) {
    int ex = sh[tid] - v;
    cstart[tid] = ex;
    gcur[tid] = ex;
  }
  if (tid == NC - 1) {
    cstart[NC] = sh[tid];
    fptr[NFB] = sh[tid];  // == E
  }
}

// 3-phase block-aggregated coarse scatter: per-(block,bucket) contiguous runs.
__global__ __launch_bounds__(256) void scatter1(const int* __restrict__ rows,
                                                const int* __restrict__ cols,
                                                const float* __restrict__ vals,
                                                int* __restrict__ gcur,
                                                int2* __restrict__ st1, int E,
                                                int NC) {
  __shared__ int lh[MAXC], gb[MAXC], lc[MAXC];
  const int tid = threadIdx.x;
  lh[tid] = 0;
  __syncthreads();
  const int base = blockIdx.x * CHUNK;
  for (int k = 0; k < CITER; ++k) {
    int e = base + k * 256 + tid;
    if (e < E) atomicAdd(&lh[rows[e] >> 9], 1);
  }
  __syncthreads();
  if (tid < NC) {
    int n = lh[tid];
    gb[tid] = n ? atomicAdd(&gcur[tid], n) : 0;
    lc[tid] = 0;
  }
  __syncthreads();
  for (int k = 0; k < CITER; ++k) {
    int e = base + k * 256 + tid;
    if (e < E) {
      int r = rows[e], c = r >> 9;
      int off = atomicAdd(&lc[c], 1);
      int2 o;
      o.x = ((r & 511) << 17) | cols[e];
      o.y = __float_as_int(vals[e]);
      st1[gb[c] + off] = o;
    }
  }
}

// Refine each coarse bucket into 8 fine (64-row) buckets; region is
// block-exclusive (~130 KB) -> L2-local writes.
__global__ __launch_bounds__(512) void scatter2(const int* __restrict__ cstart,
                                                const int2* __restrict__ st1,
                                                int2* __restrict__ st2,
                                                int* __restrict__ fptr) {
  __shared__ int cnt[8], cur[8];
  const int c = blockIdx.x, tid = threadIdx.x;
  const int a = cstart[c], b = cstart[c + 1];
  if (tid < 8) cnt[tid] = 0;
  __syncthreads();
  for (int e = a + tid; e < b; e += 512)
    atomicAdd(&cnt[(st1[e].x >> 23) & 7], 1);
  __syncthreads();
  if (tid == 0) {
    int run = a;
#pragma unroll
    for (int j = 0; j < 8; ++j) {
      fptr[c * 8 + j] = run;
      cur[j] = run;
      run += cnt[j];
    }
  }
  __syncthreads();
  for (int e = a + tid; e < b; e += 512) {
    int2 d = st1[e];
    int j = (d.x >> 23) & 7;
    int p = atomicAdd(&cur[j], 1);
    int rl = (d.x >> 17) & 63, col = d.x & 0x1FFFF;
    st2[p] = make_int2((rl << 17) | col, d.y);
  }
}

// SPMM over one fine bucket (64 rows), fp32 LDS accumulator.
// One wave per edge: lane handles features {2*lane, 2*lane+1}.
// MID: dst(bf16) = filt[row] * (A * src).  OUT: out(f32) (=/+=) A * src.
template <int MID>
__global__ __launch_bounds__(256) void spmm_b(const int* __restrict__ fptr,
                                              const int2* __restrict__ st,
                                              const unsigned short* __restrict__ src,
                                              unsigned short* __restrict__ dst,
                                              float* __restrict__ out,
                                              const float* __restrict__ filt,
                                              int N, int accm) {
  __shared__ float acc[64 * 128];
  const int tid = threadIdx.x, lane = tid & 63, wid = tid >> 6;
  for (int i = tid; i < 8192; i += 256) acc[i] = 0.f;
  __syncthreads();
  const int f = blockIdx.x;
  const int e0 = fptr[f], e1 = fptr[f + 1];
  int e = e0 + wid;
  for (; e + 4 < e1; e += 8) {
    int2 ea = st[e], eb = st[e + 4];
    int ca = ea.x & 0x1FFFF, ra = ea.x >> 17;
    int cb = eb.x & 0x1FFFF, rb = eb.x >> 17;
    float va = __int_as_float(ea.y), vb = __int_as_float(eb.y);
    unsigned sva = *(const unsigned*)(src + ((size_t)ca << 7) + (lane << 1));
    unsigned svb = *(const unsigned*)(src + ((size_t)cb << 7) + (lane << 1));
    atomicAdd(&acc[ra * 128 + (lane << 1)], va * __uint_as_float(sva << 16));
    atomicAdd(&acc[ra * 128 + (lane << 1) + 1],
              va * __uint_as_float(sva & 0xffff0000u));
    atomicAdd(&acc[rb * 128 + (lane << 1)], vb * __uint_as_float(svb << 16));
    atomicAdd(&acc[rb * 128 + (lane << 1) + 1],
              vb * __uint_as_float(svb & 0xffff0000u));
  }
  for (; e < e1; e += 4) {
    int2 ea = st[e];
    int ca = ea.x & 0x1FFFF, ra = ea.x >> 17;
    float va = __int_as_float(ea.y);
    unsigned sva = *(const unsigned*)(src + ((size_t)ca << 7) + (lane << 1));
    atomicAdd(&acc[ra * 128 + (lane << 1)], va * __uint_as_float(sva << 16));
    atomicAdd(&acc[ra * 128 + (lane << 1) + 1],
              va * __uint_as_float(sva & 0xffff0000u));
  }
  __syncthreads();
  const int rbase = f << 6;
  if (MID) {
    for (int i = tid; i < 4096; i += 256) {  // ushort2 units
      int r = i >> 6, p = i & 63;
      int row = rbase + r;
      if (row < N) {
        float fl = filt[row];
        float a0 = acc[r * 128 + 2 * p] * fl;
        float a1 = acc[r * 128 + 2 * p + 1] * fl;
        unsigned o = (unsigned)bf16bits(a0) | ((unsigned)bf16bits(a1) << 16);
        *(unsigned*)(dst + (size_t)row * 128 + 2 * p) = o;
      }
    }
  } else {
    for (int i = tid; i < 2048; i += 256) {  // float4 units
      int r = i >> 5, q = i & 31;
      int row = rbase + r;
      if (row < N) {
        float4 a = *(const float4*)&acc[r * 128 + 4 * q];
        float* op = out + (size_t)row * 128 + 4 * q;
        if (accm) {
          const float4 c4 = *(const float4*)op;
          a.x += c4.x;
          a.y += c4.y;
          a.z += c4.z;
          a.w += c4.w;
        }
        *(float4*)op = a;
      }
    }
  }
}

extern "C" void kernel_launch(void* const* d_in, const int* in_sizes, int n_in,
                              void* d_out, int out_size, void* d_ws, size_t ws_size,
                              hipStream_t stream) {
  const float* x = (const float*)d_in[0];
  const float* w = (const float*)d_in[1];
  const float* filt[3] = {(const float*)d_in[2], (const float*)d_in[3],
                          (const float*)d_in[4]};
  const int* idx[3] = {(const int*)d_in[5], (const int*)d_in[7],
                       (const int*)d_in[9]};
  const float* val[3] = {(const float*)d_in[6], (const float*)d_in[8],
                         (const float*)d_in[10]};
  const int N = in_sizes[2];
  const int E = in_sizes[6];
  float* out = (float*)d_out;

  const int NC = (N + 511) >> 9;   // coarse buckets (512 rows)
  const int NFB = NC * 8;          // fine buckets (64 rows)

  char* ws = (char*)d_ws;
  const size_t NF16 = (size_t)N * 128 * sizeof(unsigned short);
  unsigned short* xW = (unsigned short*)ws;
  unsigned short* t = (unsigned short*)(ws + NF16);
  size_t off = 2 * NF16;
  int2* st1 = (int2*)(ws + off);
  off += (size_t)E * 8;
  int2* st2 = (int2*)(ws + off);
  off += (size_t)E * 8;
  int* bcnt = (int*)(ws + off);
  off += MAXC * 4;
  int* cstart = (int*)(ws + off);
  off += (MAXC + 1) * 4;
  int* gcur = (int*)(ws + off);
  off += MAXC * 4;
  int* fptr = (int*)(ws + off);
  off += (size_t)(NFB + 1) * 4;
  (void)ws_size;  // ~103 MB needed; prior rounds confirmed >=130 MB

  gemm128<<<(N + 7) / 8, 256, 0, stream>>>(x, w, xW, N);

  const int gE = (E + CHUNK - 1) / CHUNK;
  for (int b = 0; b < 3; ++b) {
    const int* rows = idx[b];
    const int* cols = idx[b] + E;
    (void)hipMemsetAsync(bcnt, 0, (size_t)NC * 4, stream);
    bhist<<<gE, 256, 0, stream>>>(rows, bcnt, E, NC);
    bscan<<<1, 256, 0, stream>>>(bcnt, cstart, gcur, fptr, NC, NFB);
    scatter1<<<gE, 256, 0, stream>>>(rows, cols, val[b], gcur, st1, E, NC);
    scatter2<<<NC, 512, 0, stream>>>(cstart, st1, st2, fptr);
    // t = bf16(filter_b . (A_b * xW))
    spmm_b<1><<<NFB, 256, 0, stream>>>(fptr, st2, xW, t, nullptr, filt[b], N, 0);
    // out (b==0: =, else: +=) A_b * t
    spmm_b<0><<<NFB, 256, 0, stream>>>(fptr, st2, t, nullptr, out, nullptr, N,
                                       b > 0 ? 1 : 0);
  }
}

// Round 5
// 1756.496 us; speedup vs baseline: 8.2502x; 8.2502x over previous
//
#include <hip/hip_runtime.h>
#include <hip/hip_bf16.h>

// ---------------------------------------------------------------------------
// UFGConv: out = sum_b A_b * (filter_b . (A_b * (x @ W)))
// N=100000, F=128, E=3.2M per branch (3 branches).
// R5: R4's cheap hierarchical build (coarse 512-row buckets, block-aggregated
//     scatter) extended to a FULL per-row CSR via 512-bin refine (L2-local),
//     then R3's proven BW-bound per-row gather SPMM on bf16 intermediates.
//     (R4's LDS-atomic SPMM was latency-serialized: VALU 3%, HBM 2%.)
// ---------------------------------------------------------------------------

#define CHUNK 8192  // edges per hist/scatter1 block
#define CITER 32    // CHUNK / 256
#define MAXC 256    // max coarse buckets (N <= 131072)

static __device__ __forceinline__ unsigned short bf16bits(float v) {
  return __builtin_bit_cast(unsigned short, __float2bfloat16(v));
}
static __device__ __forceinline__ float bf2f(unsigned short u) {
  return __uint_as_float((unsigned)u << 16);
}

__global__ __launch_bounds__(256) void gemm128(const float* __restrict__ x,
                                               const float* __restrict__ w,
                                               unsigned short* __restrict__ y,
                                               int n) {
  __shared__ float4 wsh[128][32];
  __shared__ float xsh[8][128];
  const int tid = threadIdx.x;
  for (int i = tid; i < 128 * 32; i += 256)
    wsh[i >> 5][i & 31] = ((const float4*)w)[i];
  const int rowbase = blockIdx.x * 8;
  for (int i = tid; i < 8 * 128; i += 256) {
    int r = rowbase + (i >> 7);
    xsh[i >> 7][i & 127] = (r < n) ? x[(size_t)r * 128 + (i & 127)] : 0.f;
  }
  __syncthreads();
  const int r = tid >> 5, cg = tid & 31;
  float4 acc = {0.f, 0.f, 0.f, 0.f};
#pragma unroll
  for (int k = 0; k < 128; ++k) {
    float xv = xsh[r][k];
    float4 wv = wsh[k][cg];
    acc.x += xv * wv.x;
    acc.y += xv * wv.y;
    acc.z += xv * wv.z;
    acc.w += xv * wv.w;
  }
  if (rowbase + r < n) {
    ushort4 o;
    o.x = bf16bits(acc.x);
    o.y = bf16bits(acc.y);
    o.z = bf16bits(acc.z);
    o.w = bf16bits(acc.w);
    ((ushort4*)y)[(size_t)(rowbase + r) * 32 + cg] = o;
  }
}

// Coarse histogram: bucket = row >> 9, LDS-aggregated.
__global__ __launch_bounds__(256) void bhist(const int* __restrict__ rows,
                                             int* __restrict__ bcnt, int E,
                                             int NC) {
  __shared__ int h[MAXC];
  const int tid = threadIdx.x;
  h[tid] = 0;
  __syncthreads();
  const int base = blockIdx.x * CHUNK;
  for (int k = 0; k < CITER; ++k) {
    int e = base + k * 256 + tid;
    if (e < E) atomicAdd(&h[rows[e] >> 9], 1);
  }
  __syncthreads();
  if (tid < NC && h[tid]) atomicAdd(&bcnt[tid], h[tid]);
}

// Exclusive scan over NC coarse counts; init cursors + rowptr sentinel.
__global__ __launch_bounds__(256) void bscan(const int* __restrict__ bcnt,
                                             int* __restrict__ cstart,
                                             int* __restrict__ gcur,
                                             int* __restrict__ rowptr, int NC,
                                             int NPAD) {
  __shared__ int sh[256];
  const int tid = threadIdx.x;
  int v = (tid < NC) ? bcnt[tid] : 0;
  sh[tid] = v;
  __syncthreads();
  for (int o = 1; o < 256; o <<= 1) {
    int t2 = (tid >= o) ? sh[tid - o] : 0;
    __syncthreads();
    sh[tid] += t2;
    __syncthreads();
  }
  if (tid < NC) {
    int ex = sh[tid] - v;
    cstart[tid] = ex;
    gcur[tid] = ex;
  }
  if (tid == NC - 1) {
    cstart[NC] = sh[tid];
    rowptr[NPAD] = sh[tid];  // == E
  }
}

// 3-phase block-aggregated coarse scatter: per-(block,bucket) contiguous runs
// -> full-line writes (no 8x partial-line amplification).
__global__ __launch_bounds__(256) void scatter1(const int* __restrict__ rows,
                                                const int* __restrict__ cols,
                                                const float* __restrict__ vals,
                                                int* __restrict__ gcur,
                                                int2* __restrict__ st1, int E,
                                                int NC) {
  __shared__ int lh[MAXC], gb[MAXC], lc[MAXC];
  const int tid = threadIdx.x;
  lh[tid] = 0;
  __syncthreads();
  const int base = blockIdx.x * CHUNK;
  for (int k = 0; k < CITER; ++k) {
    int e = base + k * 256 + tid;
    if (e < E) atomicAdd(&lh[rows[e] >> 9], 1);
  }
  __syncthreads();
  if (tid < NC) {
    int n = lh[tid];
    gb[tid] = n ? atomicAdd(&gcur[tid], n) : 0;
    lc[tid] = 0;
  }
  __syncthreads();
  for (int k = 0; k < CITER; ++k) {
    int e = base + k * 256 + tid;
    if (e < E) {
      int r = rows[e], c = r >> 9;
      int off = atomicAdd(&lc[c], 1);
      int2 o;
      o.x = ((r & 511) << 17) | cols[e];
      o.y = __float_as_int(vals[e]);
      st1[gb[c] + off] = o;
    }
  }
}

// Refine each coarse bucket (512 rows, ~16K edges) into exact rows.
// Destination region is block-exclusive (~130 KB) -> L2-local full lines.
// Also emits rowptr for its 512 rows.
__global__ __launch_bounds__(512) void scatter2_rows(
    const int* __restrict__ cstart, const int2* __restrict__ st1,
    int2* __restrict__ st2, int* __restrict__ rowptr) {
  __shared__ int sh[512], cur[512];
  const int c = blockIdx.x, tid = threadIdx.x;
  const int a = cstart[c], b = cstart[c + 1];
  sh[tid] = 0;
  __syncthreads();
  for (int e = a + tid; e < b; e += 512)
    atomicAdd(&sh[(st1[e].x >> 17) & 511], 1);
  __syncthreads();
  int v = sh[tid];
  __syncthreads();
  // Hillis-Steele inclusive scan over 512 bins
  for (int o = 1; o < 512; o <<= 1) {
    int t2 = (tid >= o) ? sh[tid - o] : 0;
    __syncthreads();
    sh[tid] += t2;
    __syncthreads();
  }
  int ex = a + sh[tid] - v;  // exclusive + bucket base
  cur[tid] = ex;
  rowptr[c * 512 + tid] = ex;
  __syncthreads();
  for (int e = a + tid; e < b; e += 512) {
    int2 d = st1[e];
    int r = (d.x >> 17) & 511;
    int p = atomicAdd(&cur[r], 1);
    st2[p] = make_int2(d.x & 0x1FFFF, d.y);
  }
}

// One block (128 threads) per row; thread f owns feature f.
// dst(bf16) = filt[row] * (A * src)
__global__ __launch_bounds__(128) void spmm_mid(
    const int* __restrict__ rowptr, const int2* __restrict__ edges,
    const unsigned short* __restrict__ src, unsigned short* __restrict__ dst,
    const float* __restrict__ filt) {
  const int row = blockIdx.x;
  const int f = threadIdx.x;
  const int e0 = rowptr[row], e1 = rowptr[row + 1];
  float acc = 0.f;
  int e = e0;
  for (; e + 1 < e1; e += 2) {
    int2 d0 = edges[e], d1 = edges[e + 1];
    float s0 = bf2f(src[((size_t)d0.x << 7) + f]);
    float s1 = bf2f(src[((size_t)d1.x << 7) + f]);
    acc += __int_as_float(d0.y) * s0;
    acc += __int_as_float(d1.y) * s1;
  }
  if (e < e1) {
    int2 d = edges[e];
    acc += __int_as_float(d.y) * bf2f(src[((size_t)d.x << 7) + f]);
  }
  acc *= filt[row];
  dst[((size_t)row << 7) + f] = bf16bits(acc);
}

// out(f32) = (accm ? out : 0) + A * src
__global__ __launch_bounds__(128) void spmm_out(
    const int* __restrict__ rowptr, const int2* __restrict__ edges,
    const unsigned short* __restrict__ src, float* __restrict__ out,
    int accm) {
  const int row = blockIdx.x;
  const int f = threadIdx.x;
  const int e0 = rowptr[row], e1 = rowptr[row + 1];
  float acc = 0.f;
  int e = e0;
  for (; e + 1 < e1; e += 2) {
    int2 d0 = edges[e], d1 = edges[e + 1];
    float s0 = bf2f(src[((size_t)d0.x << 7) + f]);
    float s1 = bf2f(src[((size_t)d1.x << 7) + f]);
    acc += __int_as_float(d0.y) * s0;
    acc += __int_as_float(d1.y) * s1;
  }
  if (e < e1) {
    int2 d = edges[e];
    acc += __int_as_float(d.y) * bf2f(src[((size_t)d.x << 7) + f]);
  }
  float* o = &out[((size_t)row << 7) + f];
  *o = accm ? (*o + acc) : acc;
}

extern "C" void kernel_launch(void* const* d_in, const int* in_sizes, int n_in,
                              void* d_out, int out_size, void* d_ws, size_t ws_size,
                              hipStream_t stream) {
  const float* x = (const float*)d_in[0];
  const float* w = (const float*)d_in[1];
  const float* filt[3] = {(const float*)d_in[2], (const float*)d_in[3],
                          (const float*)d_in[4]};
  const int* idx[3] = {(const int*)d_in[5], (const int*)d_in[7],
                       (const int*)d_in[9]};
  const float* val[3] = {(const float*)d_in[6], (const float*)d_in[8],
                         (const float*)d_in[10]};
  const int N = in_sizes[2];
  const int E = in_sizes[6];
  float* out = (float*)d_out;

  const int NC = (N + 511) >> 9;  // coarse buckets (512 rows each)
  const int NPAD = NC << 9;       // padded row count

  char* ws = (char*)d_ws;
  const size_t NF16 = (size_t)N * 128 * sizeof(unsigned short);
  unsigned short* xW = (unsigned short*)ws;
  unsigned short* t = (unsigned short*)(ws + NF16);
  size_t off = 2 * NF16;
  int2* st1 = (int2*)(ws + off);
  off += (size_t)E * 8;
  int2* st2 = (int2*)(ws + off);
  off += (size_t)E * 8;
  int* bcnt = (int*)(ws + off);
  off += MAXC * 4;
  int* cstart = (int*)(ws + off);
  off += (MAXC + 1) * 4;
  int* gcur = (int*)(ws + off);
  off += MAXC * 4;
  int* rowptr = (int*)(ws + off);
  off += (size_t)(NPAD + 1) * 4;
  (void)ws_size;  // ~103 MB needed; earlier rounds confirmed available

  gemm128<<<(N + 7) / 8, 256, 0, stream>>>(x, w, xW, N);

  const int gE = (E + CHUNK - 1) / CHUNK;
  for (int b = 0; b < 3; ++b) {
    const int* rows = idx[b];
    const int* cols = idx[b] + E;
    (void)hipMemsetAsync(bcnt, 0, (size_t)NC * 4, stream);
    bhist<<<gE, 256, 0, stream>>>(rows, bcnt, E, NC);
    bscan<<<1, 256, 0, stream>>>(bcnt, cstart, gcur, rowptr, NC, NPAD);
    scatter1<<<gE, 256, 0, stream>>>(rows, cols, val[b], gcur, st1, E, NC);
    scatter2_rows<<<NC, 512, 0, stream>>>(cstart, st1, st2, rowptr);
    // t = bf16(filter_b . (A_b * xW))
    spmm_mid<<<N, 128, 0, stream>>>(rowptr, st2, xW, t, filt[b]);
    // out (b==0: =, else: +=) A_b * t
    spmm_out<<<N, 128, 0, stream>>>(rowptr, st2, t, out, b > 0 ? 1 : 0);
  }
}

// Round 6
// 1209.219 us; speedup vs baseline: 11.9841x; 1.4526x over previous
//
#include <hip/hip_runtime.h>
#include <hip/hip_bf16.h>

// ---------------------------------------------------------------------------
// UFGConv: out = sum_b A_b * (filter_b . (A_b * (x @ W)))
// N=100000, F=128, E=3.2M per branch (3 branches).
// R6: SPMM restructured to 1 wave/row, 4 B/lane packed bf16x2 gathers
//     (256 B per vmem inst = full row), 8x unrolled for MLP.
//     (R5 was issue/latency-limited: 128 B/inst, unroll 2, 2.18 TB/s.)
//     Build pipeline (hierarchical bucketing -> per-row CSR) unchanged.
// ---------------------------------------------------------------------------

#define CHUNK 8192  // edges per hist/scatter1 block
#define CITER 32    // CHUNK / 256
#define MAXC 256    // max coarse buckets (N <= 131072)

static __device__ __forceinline__ unsigned short bf16bits(float v) {
  return __builtin_bit_cast(unsigned short, __float2bfloat16(v));
}
static __device__ __forceinline__ float bflo(unsigned u) {
  return __uint_as_float(u << 16);
}
static __device__ __forceinline__ float bfhi(unsigned u) {
  return __uint_as_float(u & 0xffff0000u);
}

__global__ __launch_bounds__(256) void gemm128(const float* __restrict__ x,
                                               const float* __restrict__ w,
                                               unsigned short* __restrict__ y,
                                               int n) {
  __shared__ float4 wsh[128][32];
  __shared__ float xsh[8][128];
  const int tid = threadIdx.x;
  for (int i = tid; i < 128 * 32; i += 256)
    wsh[i >> 5][i & 31] = ((const float4*)w)[i];
  const int rowbase = blockIdx.x * 8;
  for (int i = tid; i < 8 * 128; i += 256) {
    int r = rowbase + (i >> 7);
    xsh[i >> 7][i & 127] = (r < n) ? x[(size_t)r * 128 + (i & 127)] : 0.f;
  }
  __syncthreads();
  const int r = tid >> 5, cg = tid & 31;
  float4 acc = {0.f, 0.f, 0.f, 0.f};
#pragma unroll
  for (int k = 0; k < 128; ++k) {
    float xv = xsh[r][k];
    float4 wv = wsh[k][cg];
    acc.x += xv * wv.x;
    acc.y += xv * wv.y;
    acc.z += xv * wv.z;
    acc.w += xv * wv.w;
  }
  if (rowbase + r < n) {
    ushort4 o;
    o.x = bf16bits(acc.x);
    o.y = bf16bits(acc.y);
    o.z = bf16bits(acc.z);
    o.w = bf16bits(acc.w);
    ((ushort4*)y)[(size_t)(rowbase + r) * 32 + cg] = o;
  }
}

// Coarse histogram: bucket = row >> 9, LDS-aggregated.
__global__ __launch_bounds__(256) void bhist(const int* __restrict__ rows,
                                             int* __restrict__ bcnt, int E,
                                             int NC) {
  __shared__ int h[MAXC];
  const int tid = threadIdx.x;
  h[tid] = 0;
  __syncthreads();
  const int base = blockIdx.x * CHUNK;
  for (int k = 0; k < CITER; ++k) {
    int e = base + k * 256 + tid;
    if (e < E) atomicAdd(&h[rows[e] >> 9], 1);
  }
  __syncthreads();
  if (tid < NC && h[tid]) atomicAdd(&bcnt[tid], h[tid]);
}

// Exclusive scan over NC coarse counts; init cursors + rowptr sentinel.
__global__ __launch_bounds__(256) void bscan(const int* __restrict__ bcnt,
                                             int* __restrict__ cstart,
                                             int* __restrict__ gcur,
                                             int* __restrict__ rowptr, int NC,
                                             int NPAD) {
  __shared__ int sh[256];
  const int tid = threadIdx.x;
  int v = (tid < NC) ? bcnt[tid] : 0;
  sh[tid] = v;
  __syncthreads();
  for (int o = 1; o < 256; o <<= 1) {
    int t2 = (tid >= o) ? sh[tid - o] : 0;
    __syncthreads();
    sh[tid] += t2;
    __syncthreads();
  }
  if (tid < NC) {
    int ex = sh[tid] - v;
    cstart[tid] = ex;
    gcur[tid] = ex;
  }
  if (tid == NC - 1) {
    cstart[NC] = sh[tid];
    rowptr[NPAD] = sh[tid];  // == E
  }
}

// 3-phase block-aggregated coarse scatter: per-(block,bucket) contiguous runs.
__global__ __launch_bounds__(256) void scatter1(const int* __restrict__ rows,
                                                const int* __restrict__ cols,
                                                const float* __restrict__ vals,
                                                int* __restrict__ gcur,
                                                int2* __restrict__ st1, int E,
                                                int NC) {
  __shared__ int lh[MAXC], gb[MAXC], lc[MAXC];
  const int tid = threadIdx.x;
  lh[tid] = 0;
  __syncthreads();
  const int base = blockIdx.x * CHUNK;
  for (int k = 0; k < CITER; ++k) {
    int e = base + k * 256 + tid;
    if (e < E) atomicAdd(&lh[rows[e] >> 9], 1);
  }
  __syncthreads();
  if (tid < NC) {
    int n = lh[tid];
    gb[tid] = n ? atomicAdd(&gcur[tid], n) : 0;
    lc[tid] = 0;
  }
  __syncthreads();
  for (int k = 0; k < CITER; ++k) {
    int e = base + k * 256 + tid;
    if (e < E) {
      int r = rows[e], c = r >> 9;
      int off = atomicAdd(&lc[c], 1);
      int2 o;
      o.x = ((r & 511) << 17) | cols[e];
      o.y = __float_as_int(vals[e]);
      st1[gb[c] + off] = o;
    }
  }
}

// Refine each coarse bucket (512 rows) into exact rows; emits rowptr.
__global__ __launch_bounds__(512) void scatter2_rows(
    const int* __restrict__ cstart, const int2* __restrict__ st1,
    int2* __restrict__ st2, int* __restrict__ rowptr) {
  __shared__ int sh[512], cur[512];
  const int c = blockIdx.x, tid = threadIdx.x;
  const int a = cstart[c], b = cstart[c + 1];
  sh[tid] = 0;
  __syncthreads();
  for (int e = a + tid; e < b; e += 512)
    atomicAdd(&sh[(st1[e].x >> 17) & 511], 1);
  __syncthreads();
  int v = sh[tid];
  __syncthreads();
  for (int o = 1; o < 512; o <<= 1) {
    int t2 = (tid >= o) ? sh[tid - o] : 0;
    __syncthreads();
    sh[tid] += t2;
    __syncthreads();
  }
  int ex = a + sh[tid] - v;
  cur[tid] = ex;
  rowptr[c * 512 + tid] = ex;
  __syncthreads();
  for (int e = a + tid; e < b; e += 512) {
    int2 d = st1[e];
    int r = (d.x >> 17) & 511;
    int p = atomicAdd(&cur[r], 1);
    st2[p] = make_int2(d.x & 0x1FFFF, d.y);
  }
}

// SPMM: one wave per row; lane owns features {2l, 2l+1} packed in unsigned.
// 8x unroll -> 8 independent 256 B row-gathers in flight per wave.
// MID: dst(bf16) = filt[row]*(A*src).  !MID: out(f32) (=/+=) A*src.
template <int MID>
__global__ __launch_bounds__(256) void spmm_w(
    const int* __restrict__ rowptr, const int2* __restrict__ edges,
    const unsigned short* __restrict__ src, unsigned short* __restrict__ dst,
    float* __restrict__ out, const float* __restrict__ filt, int N, int accm) {
  const int lane = threadIdx.x & 63, wid = threadIdx.x >> 6;
  const int row = blockIdx.x * 4 + wid;
  if (row >= N) return;
  const int e0 = rowptr[row], e1 = rowptr[row + 1];
  float a0 = 0.f, a1 = 0.f;
  const unsigned loff = (unsigned)(lane << 1);
  int e = e0;
  for (; e + 7 < e1; e += 8) {
    int4 p0 = *(const int4*)&edges[e];      // edges e, e+1
    int4 p1 = *(const int4*)&edges[e + 2];  // e+2, e+3
    int4 p2 = *(const int4*)&edges[e + 4];
    int4 p3 = *(const int4*)&edges[e + 6];
    unsigned u0 = *(const unsigned*)(src + (((size_t)p0.x) << 7) + loff);
    unsigned u1 = *(const unsigned*)(src + (((size_t)p0.z) << 7) + loff);
    unsigned u2 = *(const unsigned*)(src + (((size_t)p1.x) << 7) + loff);
    unsigned u3 = *(const unsigned*)(src + (((size_t)p1.z) << 7) + loff);
    unsigned u4 = *(const unsigned*)(src + (((size_t)p2.x) << 7) + loff);
    unsigned u5 = *(const unsigned*)(src + (((size_t)p2.z) << 7) + loff);
    unsigned u6 = *(const unsigned*)(src + (((size_t)p3.x) << 7) + loff);
    unsigned u7 = *(const unsigned*)(src + (((size_t)p3.z) << 7) + loff);
    float v0 = __int_as_float(p0.y), v1 = __int_as_float(p0.w);
    float v2 = __int_as_float(p1.y), v3 = __int_as_float(p1.w);
    float v4 = __int_as_float(p2.y), v5 = __int_as_float(p2.w);
    float v6 = __int_as_float(p3.y), v7 = __int_as_float(p3.w);
    a0 += v0 * bflo(u0);
    a1 += v0 * bfhi(u0);
    a0 += v1 * bflo(u1);
    a1 += v1 * bfhi(u1);
    a0 += v2 * bflo(u2);
    a1 += v2 * bfhi(u2);
    a0 += v3 * bflo(u3);
    a1 += v3 * bfhi(u3);
    a0 += v4 * bflo(u4);
    a1 += v4 * bfhi(u4);
    a0 += v5 * bflo(u5);
    a1 += v5 * bfhi(u5);
    a0 += v6 * bflo(u6);
    a1 += v6 * bfhi(u6);
    a0 += v7 * bflo(u7);
    a1 += v7 * bfhi(u7);
  }
  for (; e < e1; ++e) {
    int2 d = edges[e];
    unsigned u = *(const unsigned*)(src + (((size_t)d.x) << 7) + loff);
    float v = __int_as_float(d.y);
    a0 += v * bflo(u);
    a1 += v * bfhi(u);
  }
  if (MID) {
    float fl = filt[row];
    a0 *= fl;
    a1 *= fl;
    unsigned o = (unsigned)bf16bits(a0) | ((unsigned)bf16bits(a1) << 16);
    *(unsigned*)(dst + ((size_t)row << 7) + loff) = o;
  } else {
    float* op = out + ((size_t)row << 7) + loff;
    float2 r;
    r.x = a0;
    r.y = a1;
    if (accm) {
      float2 c = *(const float2*)op;
      r.x += c.x;
      r.y += c.y;
    }
    *(float2*)op = r;
  }
}

extern "C" void kernel_launch(void* const* d_in, const int* in_sizes, int n_in,
                              void* d_out, int out_size, void* d_ws, size_t ws_size,
                              hipStream_t stream) {
  const float* x = (const float*)d_in[0];
  const float* w = (const float*)d_in[1];
  const float* filt[3] = {(const float*)d_in[2], (const float*)d_in[3],
                          (const float*)d_in[4]};
  const int* idx[3] = {(const int*)d_in[5], (const int*)d_in[7],
                       (const int*)d_in[9]};
  const float* val[3] = {(const float*)d_in[6], (const float*)d_in[8],
                         (const float*)d_in[10]};
  const int N = in_sizes[2];
  const int E = in_sizes[6];
  float* out = (float*)d_out;

  const int NC = (N + 511) >> 9;  // coarse buckets (512 rows each)
  const int NPAD = NC << 9;       // padded row count

  char* ws = (char*)d_ws;
  const size_t NF16 = (size_t)N * 128 * sizeof(unsigned short);
  unsigned short* xW = (unsigned short*)ws;
  unsigned short* t = (unsigned short*)(ws + NF16);
  size_t off = 2 * NF16;
  int2* st1 = (int2*)(ws + off);
  off += (size_t)E * 8;
  int2* st2 = (int2*)(ws + off);
  off += (size_t)E * 8;
  int* bcnt = (int*)(ws + off);
  off += MAXC * 4;
  int* cstart = (int*)(ws + off);
  off += (MAXC + 1) * 4;
  int* gcur = (int*)(ws + off);
  off += MAXC * 4;
  int* rowptr = (int*)(ws + off);
  off += (size_t)(NPAD + 1) * 4;
  (void)ws_size;  // ~103 MB needed; earlier rounds confirmed available

  gemm128<<<(N + 7) / 8, 256, 0, stream>>>(x, w, xW, N);

  const int gE = (E + CHUNK - 1) / CHUNK;
  const int gS = (N + 3) / 4;
  for (int b = 0; b < 3; ++b) {
    const int* rows = idx[b];
    const int* cols = idx[b] + E;
    (void)hipMemsetAsync(bcnt, 0, (size_t)NC * 4, stream);
    bhist<<<gE, 256, 0, stream>>>(rows, bcnt, E, NC);
    bscan<<<1, 256, 0, stream>>>(bcnt, cstart, gcur, rowptr, NC, NPAD);
    scatter1<<<gE, 256, 0, stream>>>(rows, cols, val[b], gcur, st1, E, NC);
    scatter2_rows<<<NC, 512, 0, stream>>>(cstart, st1, st2, rowptr);
    // t = bf16(filter_b . (A_b * xW))
    spmm_w<1><<<gS, 256, 0, stream>>>(rowptr, st2, xW, t, nullptr, filt[b], N, 0);
    // out (b==0: =, else: +=) A_b * t
    spmm_w<0><<<gS, 256, 0, stream>>>(rowptr, st2, t, nullptr, out, nullptr, N,
                                      b > 0 ? 1 : 0);
  }
}

// Round 7
// 1081.421 us; speedup vs baseline: 13.4003x; 1.1182x over previous
//
#include <hip/hip_runtime.h>
#include <hip/hip_bf16.h>

// ---------------------------------------------------------------------------
// UFGConv: out = sum_b A_b * (filter_b . (A_b * (x @ W)))
// N=100000, F=128, E=3.2M per branch (3 branches).
// R7: MFMA GEMM (16x16x32 bf16): 128x128 tile/block, W^T staged bf16 in LDS
//     (34 KB -> 4 blocks/CU), A-frags straight from global. Replaces the
//     LDS-latency-bound vector GEMM (190 us, 22% occupancy, 9x off roofline).
//     SPMM + hierarchical CSR build unchanged from R6.
// ---------------------------------------------------------------------------

#define CHUNK 8192  // edges per hist/scatter1 block
#define CITER 32    // CHUNK / 256
#define MAXC 256    // max coarse buckets (N <= 131072)

typedef __attribute__((ext_vector_type(8))) short short8;
typedef __attribute__((ext_vector_type(4))) float f32x4;

static __device__ __forceinline__ unsigned short bf16bits(float v) {
  return __builtin_bit_cast(unsigned short, __float2bfloat16(v));
}
static __device__ __forceinline__ float bflo(unsigned u) {
  return __uint_as_float(u << 16);
}
static __device__ __forceinline__ float bfhi(unsigned u) {
  return __uint_as_float(u & 0xffff0000u);
}

// MFMA GEMM: y[n][128] (bf16) = x[n][128] (f32) @ w[128][128] (f32).
// Block: 256 thr = 4 waves; 128 rows x 128 cols per block.
// Wave: 32 rows x 128 cols = 2x8 tiles of 16x16, K-loop 4 steps of 32.
__global__ __launch_bounds__(256) void gemm_mfma(const float* __restrict__ x,
                                                 const float* __restrict__ w,
                                                 unsigned short* __restrict__ y,
                                                 int n) {
  __shared__ unsigned short wt[128][136];  // W^T [col][k], pad 136 (272 B rows)
  const int tid = threadIdx.x;
  // Stage W^T as bf16: 4096 float4 reads of W row-major, scatter to wt.
#pragma unroll
  for (int it = 0; it < 16; ++it) {
    int i = it * 256 + tid;      // float4 index in W
    int k = i >> 5;              // 32 float4 per k-row
    int c4 = (i & 31) << 2;      // col base
    float4 v = ((const float4*)w)[i];
    wt[c4 + 0][k] = bf16bits(v.x);
    wt[c4 + 1][k] = bf16bits(v.y);
    wt[c4 + 2][k] = bf16bits(v.z);
    wt[c4 + 3][k] = bf16bits(v.w);
  }
  __syncthreads();
  const int lane = tid & 63, wid = tid >> 6;
  const int lr = lane & 15, lq = lane >> 4;
  const int rowbase = blockIdx.x * 128 + wid * 32;
  f32x4 acc[2][8] = {};
#pragma unroll
  for (int ks = 0; ks < 4; ++ks) {
    short8 a[2];
#pragma unroll
    for (int s = 0; s < 2; ++s) {
      int r = rowbase + s * 16 + lr;
      float4 v0 = {0.f, 0.f, 0.f, 0.f}, v1 = {0.f, 0.f, 0.f, 0.f};
      if (r < n) {
        const float* xp = x + (size_t)r * 128 + ks * 32 + lq * 8;
        v0 = *(const float4*)xp;
        v1 = *(const float4*)(xp + 4);
      }
      a[s][0] = bf16bits(v0.x);
      a[s][1] = bf16bits(v0.y);
      a[s][2] = bf16bits(v0.z);
      a[s][3] = bf16bits(v0.w);
      a[s][4] = bf16bits(v1.x);
      a[s][5] = bf16bits(v1.y);
      a[s][6] = bf16bits(v1.z);
      a[s][7] = bf16bits(v1.w);
    }
#pragma unroll
    for (int cs = 0; cs < 8; ++cs) {
      short8 b = *(const short8*)&wt[cs * 16 + lr][ks * 32 + lq * 8];
      acc[0][cs] =
          __builtin_amdgcn_mfma_f32_16x16x32_bf16(a[0], b, acc[0][cs], 0, 0, 0);
      acc[1][cs] =
          __builtin_amdgcn_mfma_f32_16x16x32_bf16(a[1], b, acc[1][cs], 0, 0, 0);
    }
  }
  // Epilogue: D layout col=lane&15, row=(lane>>4)*4+reg (m89-verified).
#pragma unroll
  for (int s = 0; s < 2; ++s) {
#pragma unroll
    for (int cs = 0; cs < 8; ++cs) {
      int col = cs * 16 + lr;
      int r0 = rowbase + s * 16 + lq * 4;
#pragma unroll
      for (int j = 0; j < 4; ++j) {
        int r = r0 + j;
        if (r < n) y[(size_t)r * 128 + col] = bf16bits(acc[s][cs][j]);
      }
    }
  }
}

// Coarse histogram: bucket = row >> 9, LDS-aggregated.
__global__ __launch_bounds__(256) void bhist(const int* __restrict__ rows,
                                             int* __restrict__ bcnt, int E,
                                             int NC) {
  __shared__ int h[MAXC];
  const int tid = threadIdx.x;
  h[tid] = 0;
  __syncthreads();
  const int base = blockIdx.x * CHUNK;
  for (int k = 0; k < CITER; ++k) {
    int e = base + k * 256 + tid;
    if (e < E) atomicAdd(&h[rows[e] >> 9], 1);
  }
  __syncthreads();
  if (tid < NC && h[tid]) atomicAdd(&bcnt[tid], h[tid]);
}

// Exclusive scan over NC coarse counts; init cursors + rowptr sentinel.
__global__ __launch_bounds__(256) void bscan(const int* __restrict__ bcnt,
                                             int* __restrict__ cstart,
                                             int* __restrict__ gcur,
                                             int* __restrict__ rowptr, int NC,
                                             int NPAD) {
  __shared__ int sh[256];
  const int tid = threadIdx.x;
  int v = (tid < NC) ? bcnt[tid] : 0;
  sh[tid] = v;
  __syncthreads();
  for (int o = 1; o < 256; o <<= 1) {
    int t2 = (tid >= o) ? sh[tid - o] : 0;
    __syncthreads();
    sh[tid] += t2;
    __syncthreads();
  }
  if (tid < NC) {
    int ex = sh[tid] - v;
    cstart[tid] = ex;
    gcur[tid] = ex;
  }
  if (tid == NC - 1) {
    cstart[NC] = sh[tid];
    rowptr[NPAD] = sh[tid];  // == E
  }
}

// 3-phase block-aggregated coarse scatter: per-(block,bucket) contiguous runs.
__global__ __launch_bounds__(256) void scatter1(const int* __restrict__ rows,
                                                const int* __restrict__ cols,
                                                const float* __restrict__ vals,
                                                int* __restrict__ gcur,
                                                int2* __restrict__ st1, int E,
                                                int NC) {
  __shared__ int lh[MAXC], gb[MAXC], lc[MAXC];
  const int tid = threadIdx.x;
  lh[tid] = 0;
  __syncthreads();
  const int base = blockIdx.x * CHUNK;
  for (int k = 0; k < CITER; ++k) {
    int e = base + k * 256 + tid;
    if (e < E) atomicAdd(&lh[rows[e] >> 9], 1);
  }
  __syncthreads();
  if (tid < NC) {
    int n = lh[tid];
    gb[tid] = n ? atomicAdd(&gcur[tid], n) : 0;
    lc[tid] = 0;
  }
  __syncthreads();
  for (int k = 0; k < CITER; ++k) {
    int e = base + k * 256 + tid;
    if (e < E) {
      int r = rows[e], c = r >> 9;
      int off = atomicAdd(&lc[c], 1);
      int2 o;
      o.x = ((r & 511) << 17) | cols[e];
      o.y = __float_as_int(vals[e]);
      st1[gb[c] + off] = o;
    }
  }
}

// Refine each coarse bucket (512 rows) into exact rows; emits rowptr.
__global__ __launch_bounds__(512) void scatter2_rows(
    const int* __restrict__ cstart, const int2* __restrict__ st1,
    int2* __restrict__ st2, int* __restrict__ rowptr) {
  __shared__ int sh[512], cur[512];
  const int c = blockIdx.x, tid = threadIdx.x;
  const int a = cstart[c], b = cstart[c + 1];
  sh[tid] = 0;
  __syncthreads();
  for (int e = a + tid; e < b; e += 512)
    atomicAdd(&sh[(st1[e].x >> 17) & 511], 1);
  __syncthreads();
  int v = sh[tid];
  __syncthreads();
  for (int o = 1; o < 512; o <<= 1) {
    int t2 = (tid >= o) ? sh[tid - o] : 0;
    __syncthreads();
    sh[tid] += t2;
    __syncthreads();
  }
  int ex = a + sh[tid] - v;
  cur[tid] = ex;
  rowptr[c * 512 + tid] = ex;
  __syncthreads();
  for (int e = a + tid; e < b; e += 512) {
    int2 d = st1[e];
    int r = (d.x >> 17) & 511;
    int p = atomicAdd(&cur[r], 1);
    st2[p] = make_int2(d.x & 0x1FFFF, d.y);
  }
}

// SPMM: one wave per row; lane owns features {2l, 2l+1} packed in unsigned.
// 8x unroll -> 8 independent 256 B row-gathers in flight per wave.
// MID: dst(bf16) = filt[row]*(A*src).  !MID: out(f32) (=/+=) A*src.
template <int MID>
__global__ __launch_bounds__(256) void spmm_w(
    const int* __restrict__ rowptr, const int2* __restrict__ edges,
    const unsigned short* __restrict__ src, unsigned short* __restrict__ dst,
    float* __restrict__ out, const float* __restrict__ filt, int N, int accm) {
  const int lane = threadIdx.x & 63, wid = threadIdx.x >> 6;
  const int row = blockIdx.x * 4 + wid;
  if (row >= N) return;
  const int e0 = rowptr[row], e1 = rowptr[row + 1];
  float a0 = 0.f, a1 = 0.f;
  const unsigned loff = (unsigned)(lane << 1);
  int e = e0;
  for (; e + 7 < e1; e += 8) {
    int4 p0 = *(const int4*)&edges[e];
    int4 p1 = *(const int4*)&edges[e + 2];
    int4 p2 = *(const int4*)&edges[e + 4];
    int4 p3 = *(const int4*)&edges[e + 6];
    unsigned u0 = *(const unsigned*)(src + (((size_t)p0.x) << 7) + loff);
    unsigned u1 = *(const unsigned*)(src + (((size_t)p0.z) << 7) + loff);
    unsigned u2 = *(const unsigned*)(src + (((size_t)p1.x) << 7) + loff);
    unsigned u3 = *(const unsigned*)(src + (((size_t)p1.z) << 7) + loff);
    unsigned u4 = *(const unsigned*)(src + (((size_t)p2.x) << 7) + loff);
    unsigned u5 = *(const unsigned*)(src + (((size_t)p2.z) << 7) + loff);
    unsigned u6 = *(const unsigned*)(src + (((size_t)p3.x) << 7) + loff);
    unsigned u7 = *(const unsigned*)(src + (((size_t)p3.z) << 7) + loff);
    float v0 = __int_as_float(p0.y), v1 = __int_as_float(p0.w);
    float v2 = __int_as_float(p1.y), v3 = __int_as_float(p1.w);
    float v4 = __int_as_float(p2.y), v5 = __int_as_float(p2.w);
    float v6 = __int_as_float(p3.y), v7 = __int_as_float(p3.w);
    a0 += v0 * bflo(u0);
    a1 += v0 * bfhi(u0);
    a0 += v1 * bflo(u1);
    a1 += v1 * bfhi(u1);
    a0 += v2 * bflo(u2);
    a1 += v2 * bfhi(u2);
    a0 += v3 * bflo(u3);
    a1 += v3 * bfhi(u3);
    a0 += v4 * bflo(u4);
    a1 += v4 * bfhi(u4);
    a0 += v5 * bflo(u5);
    a1 += v5 * bfhi(u5);
    a0 += v6 * bflo(u6);
    a1 += v6 * bfhi(u6);
    a0 += v7 * bflo(u7);
    a1 += v7 * bfhi(u7);
  }
  for (; e < e1; ++e) {
    int2 d = edges[e];
    unsigned u = *(const unsigned*)(src + (((size_t)d.x) << 7) + loff);
    float v = __int_as_float(d.y);
    a0 += v * bflo(u);
    a1 += v * bfhi(u);
  }
  if (MID) {
    float fl = filt[row];
    a0 *= fl;
    a1 *= fl;
    unsigned o = (unsigned)bf16bits(a0) | ((unsigned)bf16bits(a1) << 16);
    *(unsigned*)(dst + ((size_t)row << 7) + loff) = o;
  } else {
    float* op = out + ((size_t)row << 7) + loff;
    float2 r;
    r.x = a0;
    r.y = a1;
    if (accm) {
      float2 c = *(const float2*)op;
      r.x += c.x;
      r.y += c.y;
    }
    *(float2*)op = r;
  }
}

extern "C" void kernel_launch(void* const* d_in, const int* in_sizes, int n_in,
                              void* d_out, int out_size, void* d_ws, size_t ws_size,
                              hipStream_t stream) {
  const float* x = (const float*)d_in[0];
  const float* w = (const float*)d_in[1];
  const float* filt[3] = {(const float*)d_in[2], (const float*)d_in[3],
                          (const float*)d_in[4]};
  const int* idx[3] = {(const int*)d_in[5], (const int*)d_in[7],
                       (const int*)d_in[9]};
  const float* val[3] = {(const float*)d_in[6], (const float*)d_in[8],
                         (const float*)d_in[10]};
  const int N = in_sizes[2];
  const int E = in_sizes[6];
  float* out = (float*)d_out;

  const int NC = (N + 511) >> 9;  // coarse buckets (512 rows each)
  const int NPAD = NC << 9;       // padded row count

  char* ws = (char*)d_ws;
  const size_t NF16 = (size_t)N * 128 * sizeof(unsigned short);
  unsigned short* xW = (unsigned short*)ws;
  unsigned short* t = (unsigned short*)(ws + NF16);
  size_t off = 2 * NF16;
  int2* st1 = (int2*)(ws + off);
  off += (size_t)E * 8;
  int2* st2 = (int2*)(ws + off);
  off += (size_t)E * 8;
  int* bcnt = (int*)(ws + off);
  off += MAXC * 4;
  int* cstart = (int*)(ws + off);
  off += (MAXC + 1) * 4;
  int* gcur = (int*)(ws + off);
  off += MAXC * 4;
  int* rowptr = (int*)(ws + off);
  off += (size_t)(NPAD + 1) * 4;
  (void)ws_size;  // ~103 MB needed; earlier rounds confirmed available

  gemm_mfma<<<(N + 127) / 128, 256, 0, stream>>>(x, w, xW, N);

  const int gE = (E + CHUNK - 1) / CHUNK;
  const int gS = (N + 3) / 4;
  for (int b = 0; b < 3; ++b) {
    const int* rows = idx[b];
    const int* cols = idx[b] + E;
    (void)hipMemsetAsync(bcnt, 0, (size_t)NC * 4, stream);
    bhist<<<gE, 256, 0, stream>>>(rows, bcnt, E, NC);
    bscan<<<1, 256, 0, stream>>>(bcnt, cstart, gcur, rowptr, NC, NPAD);
    scatter1<<<gE, 256, 0, stream>>>(rows, cols, val[b], gcur, st1, E, NC);
    scatter2_rows<<<NC, 512, 0, stream>>>(cstart, st1, st2, rowptr);
    // t = bf16(filter_b . (A_b * xW))
    spmm_w<1><<<gS, 256, 0, stream>>>(rowptr, st2, xW, t, nullptr, filt[b], N, 0);
    // out (b==0: =, else: +=) A_b * t
    spmm_w<0><<<gS, 256, 0, stream>>>(rowptr, st2, t, nullptr, out, nullptr, N,
                                      b > 0 ? 1 : 0);
  }
}

// Round 9
// 1065.508 us; speedup vs baseline: 13.6004x; 1.0149x over previous
//
#include <hip/hip_runtime.h>
#include <hip/hip_bf16.h>

// ---------------------------------------------------------------------------
// UFGConv: out = sum_b A_b * (filter_b . (A_b * (x @ W)))
// N=100000, F=128, E=3.2M per branch (3 branches).
// R9: R8 with ext_vector int4v for nontemporal loads (HIP int4 is a struct,
//     rejected by __builtin_nontemporal_load).
//     Fixed-capacity buckets (no hist/scan/memset), CHUNK 4096, SPMM
//     unroll 16 + nt edge loads + split accumulators. GEMM = R7 MFMA.
// ---------------------------------------------------------------------------

#define CHUNK 4096  // edges per scatter1 block
#define CITER 16    // CHUNK / 256
#define MAXC 256    // max coarse buckets (N <= 131072)

typedef __attribute__((ext_vector_type(8))) short short8;
typedef __attribute__((ext_vector_type(4))) float f32x4;
typedef __attribute__((ext_vector_type(4))) int int4v;

static __device__ __forceinline__ unsigned short bf16bits(float v) {
  return __builtin_bit_cast(unsigned short, __float2bfloat16(v));
}
static __device__ __forceinline__ float bflo(unsigned u) {
  return __uint_as_float(u << 16);
}
static __device__ __forceinline__ float bfhi(unsigned u) {
  return __uint_as_float(u & 0xffff0000u);
}

// MFMA GEMM: y[n][128] (bf16) = x[n][128] (f32) @ w[128][128] (f32).
__global__ __launch_bounds__(256) void gemm_mfma(const float* __restrict__ x,
                                                 const float* __restrict__ w,
                                                 unsigned short* __restrict__ y,
                                                 int n) {
  __shared__ unsigned short wt[128][136];  // W^T [col][k], pad 136
  const int tid = threadIdx.x;
#pragma unroll
  for (int it = 0; it < 16; ++it) {
    int i = it * 256 + tid;
    int k = i >> 5;
    int c4 = (i & 31) << 2;
    float4 v = ((const float4*)w)[i];
    wt[c4 + 0][k] = bf16bits(v.x);
    wt[c4 + 1][k] = bf16bits(v.y);
    wt[c4 + 2][k] = bf16bits(v.z);
    wt[c4 + 3][k] = bf16bits(v.w);
  }
  __syncthreads();
  const int lane = tid & 63, wid = tid >> 6;
  const int lr = lane & 15, lq = lane >> 4;
  const int rowbase = blockIdx.x * 128 + wid * 32;
  f32x4 acc[2][8] = {};
#pragma unroll
  for (int ks = 0; ks < 4; ++ks) {
    short8 a[2];
#pragma unroll
    for (int s = 0; s < 2; ++s) {
      int r = rowbase + s * 16 + lr;
      float4 v0 = {0.f, 0.f, 0.f, 0.f}, v1 = {0.f, 0.f, 0.f, 0.f};
      if (r < n) {
        const float* xp = x + (size_t)r * 128 + ks * 32 + lq * 8;
        v0 = *(const float4*)xp;
        v1 = *(const float4*)(xp + 4);
      }
      a[s][0] = bf16bits(v0.x);
      a[s][1] = bf16bits(v0.y);
      a[s][2] = bf16bits(v0.z);
      a[s][3] = bf16bits(v0.w);
      a[s][4] = bf16bits(v1.x);
      a[s][5] = bf16bits(v1.y);
      a[s][6] = bf16bits(v1.z);
      a[s][7] = bf16bits(v1.w);
    }
#pragma unroll
    for (int cs = 0; cs < 8; ++cs) {
      short8 b = *(const short8*)&wt[cs * 16 + lr][ks * 32 + lq * 8];
      acc[0][cs] =
          __builtin_amdgcn_mfma_f32_16x16x32_bf16(a[0], b, acc[0][cs], 0, 0, 0);
      acc[1][cs] =
          __builtin_amdgcn_mfma_f32_16x16x32_bf16(a[1], b, acc[1][cs], 0, 0, 0);
    }
  }
#pragma unroll
  for (int s = 0; s < 2; ++s) {
#pragma unroll
    for (int cs = 0; cs < 8; ++cs) {
      int col = cs * 16 + lr;
      int r0 = rowbase + s * 16 + lq * 4;
#pragma unroll
      for (int j = 0; j < 4; ++j) {
        int r = r0 + j;
        if (r < n) y[(size_t)r * 128 + col] = bf16bits(acc[s][cs][j]);
      }
    }
  }
}

// Init per-bucket append cursors to bucket bases.
__global__ void ginit(int* __restrict__ gcur, int NC, int CAP) {
  int i = blockIdx.x * 256 + threadIdx.x;
  if (i < NC) gcur[i] = i * CAP;
}

// Block-aggregated coarse scatter into fixed-capacity bucket regions.
__global__ __launch_bounds__(256) void scatter1(const int* __restrict__ rows,
                                                const int* __restrict__ cols,
                                                const float* __restrict__ vals,
                                                int* __restrict__ gcur,
                                                int2* __restrict__ st1, int E,
                                                int NC) {
  __shared__ int lh[MAXC], gb[MAXC], lc[MAXC];
  __shared__ int rc[CHUNK];
  const int tid = threadIdx.x;
  lh[tid] = 0;
  __syncthreads();
  const int base = blockIdx.x * CHUNK;
#pragma unroll
  for (int k = 0; k < CITER; ++k) {
    int e = base + k * 256 + tid;
    int r = -1;
    if (e < E) {
      r = __builtin_nontemporal_load(rows + e);
      atomicAdd(&lh[r >> 9], 1);
    }
    rc[k * 256 + tid] = r;
  }
  __syncthreads();
  if (tid < NC) {
    int n = lh[tid];
    gb[tid] = n ? atomicAdd(&gcur[tid], n) : 0;
    lc[tid] = 0;
  }
  __syncthreads();
#pragma unroll
  for (int k = 0; k < CITER; ++k) {
    int e = base + k * 256 + tid;
    int r = rc[k * 256 + tid];
    if (r >= 0) {
      int c = r >> 9;
      int off = atomicAdd(&lc[c], 1);
      int2 o;
      o.x = ((r & 511) << 17) | __builtin_nontemporal_load(cols + e);
      o.y = __float_as_int(__builtin_nontemporal_load(vals + e));
      st1[gb[c] + off] = o;
    }
  }
}

// Refine each coarse bucket into exact rows; emit per-row {start,end}.
__global__ __launch_bounds__(512) void scatter2(const int* __restrict__ gcur,
                                                const int2* __restrict__ st1,
                                                int2* __restrict__ st2,
                                                int2* __restrict__ rowse,
                                                int CAP) {
  __shared__ int sh[512], cur[512];
  const int c = blockIdx.x, tid = threadIdx.x;
  const int a = c * CAP;
  const int b = gcur[c];  // a + count
  sh[tid] = 0;
  __syncthreads();
  for (int e = a + tid; e < b; e += 512)
    atomicAdd(&sh[(st1[e].x >> 17) & 511], 1);
  __syncthreads();
  int v = sh[tid];
  __syncthreads();
  for (int o = 1; o < 512; o <<= 1) {
    int t2 = (tid >= o) ? sh[tid - o] : 0;
    __syncthreads();
    sh[tid] += t2;
    __syncthreads();
  }
  int end = a + sh[tid];
  int start = end - v;
  cur[tid] = start;
  rowse[c * 512 + tid] = make_int2(start, end);
  __syncthreads();
  for (int e = a + tid; e < b; e += 512) {
    int2 d = st1[e];
    int r = (d.x >> 17) & 511;
    int p = atomicAdd(&cur[r], 1);
    st2[p] = make_int2(d.x & 0x1FFFF, d.y);
  }
}

// SPMM: one wave per row; lane owns features {2l,2l+1} packed (256 B/gather).
// 16-deep unroll, nt edge loads, split accumulator banks.
// MID: dst(bf16)=filt[row]*(A*src).  !MID: out(f32) (=/+=) A*src.
template <int MID>
__global__ __launch_bounds__(256) void spmm_w(
    const int2* __restrict__ rowse, const int2* __restrict__ edges,
    const unsigned short* __restrict__ src, unsigned short* __restrict__ dst,
    float* __restrict__ out, const float* __restrict__ filt, int N, int accm) {
  const int lane = threadIdx.x & 63, wid = threadIdx.x >> 6;
  const int row = blockIdx.x * 4 + wid;
  if (row >= N) return;
  const int2 se = rowse[row];
  int e = se.x;
  const int e1 = se.y;
  float a0 = 0.f, a1 = 0.f, b0 = 0.f, b1 = 0.f;
  const unsigned loff = (unsigned)(lane << 1);
  for (; e + 15 < e1; e += 16) {
    int4v p[8];
#pragma unroll
    for (int j = 0; j < 8; ++j)
      p[j] = __builtin_nontemporal_load((const int4v*)&edges[e + 2 * j]);
    unsigned u[16];
#pragma unroll
    for (int j = 0; j < 8; ++j) {
      u[2 * j] = *(const unsigned*)(src + (((size_t)p[j].x) << 7) + loff);
      u[2 * j + 1] = *(const unsigned*)(src + (((size_t)p[j].z) << 7) + loff);
    }
#pragma unroll
    for (int j = 0; j < 8; ++j) {
      float v0 = __int_as_float(p[j].y), v1 = __int_as_float(p[j].w);
      if (j & 1) {
        b0 += v0 * bflo(u[2 * j]);
        b1 += v0 * bfhi(u[2 * j]);
        b0 += v1 * bflo(u[2 * j + 1]);
        b1 += v1 * bfhi(u[2 * j + 1]);
      } else {
        a0 += v0 * bflo(u[2 * j]);
        a1 += v0 * bfhi(u[2 * j]);
        a0 += v1 * bflo(u[2 * j + 1]);
        a1 += v1 * bfhi(u[2 * j + 1]);
      }
    }
  }
  for (; e + 3 < e1; e += 4) {
    int4v pa = __builtin_nontemporal_load((const int4v*)&edges[e]);
    int4v pb = __builtin_nontemporal_load((const int4v*)&edges[e + 2]);
    unsigned u0 = *(const unsigned*)(src + (((size_t)pa.x) << 7) + loff);
    unsigned u1 = *(const unsigned*)(src + (((size_t)pa.z) << 7) + loff);
    unsigned u2 = *(const unsigned*)(src + (((size_t)pb.x) << 7) + loff);
    unsigned u3 = *(const unsigned*)(src + (((size_t)pb.z) << 7) + loff);
    float v0 = __int_as_float(pa.y), v1 = __int_as_float(pa.w);
    float v2 = __int_as_float(pb.y), v3 = __int_as_float(pb.w);
    a0 += v0 * bflo(u0);
    a1 += v0 * bfhi(u0);
    b0 += v1 * bflo(u1);
    b1 += v1 * bfhi(u1);
    a0 += v2 * bflo(u2);
    a1 += v2 * bfhi(u2);
    b0 += v3 * bflo(u3);
    b1 += v3 * bfhi(u3);
  }
  for (; e < e1; ++e) {
    int2 d = edges[e];
    unsigned u = *(const unsigned*)(src + (((size_t)d.x) << 7) + loff);
    float v = __int_as_float(d.y);
    a0 += v * bflo(u);
    a1 += v * bfhi(u);
  }
  a0 += b0;
  a1 += b1;
  if (MID) {
    float fl = filt[row];
    a0 *= fl;
    a1 *= fl;
    unsigned o = (unsigned)bf16bits(a0) | ((unsigned)bf16bits(a1) << 16);
    *(unsigned*)(dst + ((size_t)row << 7) + loff) = o;
  } else {
    float* op = out + ((size_t)row << 7) + loff;
    float2 r;
    r.x = a0;
    r.y = a1;
    if (accm) {
      float2 c = *(const float2*)op;
      r.x += c.x;
      r.y += c.y;
    }
    *(float2*)op = r;
  }
}

extern "C" void kernel_launch(void* const* d_in, const int* in_sizes, int n_in,
                              void* d_out, int out_size, void* d_ws, size_t ws_size,
                              hipStream_t stream) {
  const float* x = (const float*)d_in[0];
  const float* w = (const float*)d_in[1];
  const float* filt[3] = {(const float*)d_in[2], (const float*)d_in[3],
                          (const float*)d_in[4]};
  const int* idx[3] = {(const int*)d_in[5], (const int*)d_in[7],
                       (const int*)d_in[9]};
  const float* val[3] = {(const float*)d_in[6], (const float*)d_in[8],
                         (const float*)d_in[10]};
  const int N = in_sizes[2];
  const int E = in_sizes[6];
  float* out = (float*)d_out;

  const int NC = (N + 511) >> 9;  // coarse buckets (512 rows each)
  // Fixed bucket capacity: mean + 4096 (~32 sigma for uniform random rows).
  const int CAP = (((E + NC - 1) / NC) + 4096 + 255) & ~255;

  char* ws = (char*)d_ws;
  const size_t NF16 = (size_t)N * 128 * sizeof(unsigned short);
  unsigned short* xW = (unsigned short*)ws;
  unsigned short* t = (unsigned short*)(ws + NF16);
  size_t off = 2 * NF16;
  int2* st1 = (int2*)(ws + off);
  off += (size_t)NC * CAP * 8;
  int2* st2 = (int2*)(ws + off);
  off += (size_t)NC * CAP * 8;
  int* gcur = (int*)(ws + off);
  off += (MAXC * 4 + 255) & ~(size_t)255;
  int2* rowse = (int2*)(ws + off);
  off += (size_t)(NC << 9) * 8;
  (void)ws_size;  // ~116 MB needed; >=129 MB proven available (R1)

  gemm_mfma<<<(N + 127) / 128, 256, 0, stream>>>(x, w, xW, N);

  const int gE = (E + CHUNK - 1) / CHUNK;
  const int gS = (N + 3) / 4;
  for (int b = 0; b < 3; ++b) {
    const int* rows = idx[b];
    const int* cols = idx[b] + E;
    ginit<<<(NC + 255) / 256, 256, 0, stream>>>(gcur, NC, CAP);
    scatter1<<<gE, 256, 0, stream>>>(rows, cols, val[b], gcur, st1, E, NC);
    scatter2<<<NC, 512, 0, stream>>>(gcur, st1, st2, rowse, CAP);
    // t = bf16(filter_b . (A_b * xW))
    spmm_w<1><<<gS, 256, 0, stream>>>(rowse, st2, xW, t, nullptr, filt[b], N, 0);
    // out (b==0: =, else: +=) A_b * t
    spmm_w<0><<<gS, 256, 0, stream>>>(rowse, st2, t, nullptr, out, nullptr, N,
                                      b > 0 ? 1 : 0);
  }
}

// Round 10
// 1026.543 us; speedup vs baseline: 14.1167x; 1.0380x over previous
//
#include <hip/hip_runtime.h>
#include <hip/hip_bf16.h>

// ---------------------------------------------------------------------------
// UFGConv: out = sum_b A_b * (filter_b . (A_b * (x @ W)))
// N=100000, F=128, E=3.2M per branch (3 branches).
// R10: revert SPMM to R7 operating point (8-deep, plain loads, VGPR 28,
//      occ 75% -- R9's 16-deep+nt traded TLP for ILP at a loss), fuse the
//      three out-SPMMs into spmm_out3 (kills 205 MB of out RMW traffic),
//      gated on ws_size with exact per-branch fallback. CAP margin 16sigma.
// ---------------------------------------------------------------------------

#define CHUNK 4096  // edges per scatter1 block
#define CITER 16    // CHUNK / 256
#define MAXC 256    // max coarse buckets (N <= 131072)

typedef __attribute__((ext_vector_type(8))) short short8;
typedef __attribute__((ext_vector_type(4))) float f32x4;

static __device__ __forceinline__ unsigned short bf16bits(float v) {
  return __builtin_bit_cast(unsigned short, __float2bfloat16(v));
}
static __device__ __forceinline__ float bflo(unsigned u) {
  return __uint_as_float(u << 16);
}
static __device__ __forceinline__ float bfhi(unsigned u) {
  return __uint_as_float(u & 0xffff0000u);
}

// MFMA GEMM: y[n][128] (bf16) = x[n][128] (f32) @ w[128][128] (f32).
__global__ __launch_bounds__(256) void gemm_mfma(const float* __restrict__ x,
                                                 const float* __restrict__ w,
                                                 unsigned short* __restrict__ y,
                                                 int n) {
  __shared__ unsigned short wt[128][136];  // W^T [col][k], pad 136
  const int tid = threadIdx.x;
#pragma unroll
  for (int it = 0; it < 16; ++it) {
    int i = it * 256 + tid;
    int k = i >> 5;
    int c4 = (i & 31) << 2;
    float4 v = ((const float4*)w)[i];
    wt[c4 + 0][k] = bf16bits(v.x);
    wt[c4 + 1][k] = bf16bits(v.y);
    wt[c4 + 2][k] = bf16bits(v.z);
    wt[c4 + 3][k] = bf16bits(v.w);
  }
  __syncthreads();
  const int lane = tid & 63, wid = tid >> 6;
  const int lr = lane & 15, lq = lane >> 4;
  const int rowbase = blockIdx.x * 128 + wid * 32;
  f32x4 acc[2][8] = {};
#pragma unroll
  for (int ks = 0; ks < 4; ++ks) {
    short8 a[2];
#pragma unroll
    for (int s = 0; s < 2; ++s) {
      int r = rowbase + s * 16 + lr;
      float4 v0 = {0.f, 0.f, 0.f, 0.f}, v1 = {0.f, 0.f, 0.f, 0.f};
      if (r < n) {
        const float* xp = x + (size_t)r * 128 + ks * 32 + lq * 8;
        v0 = *(const float4*)xp;
        v1 = *(const float4*)(xp + 4);
      }
      a[s][0] = bf16bits(v0.x);
      a[s][1] = bf16bits(v0.y);
      a[s][2] = bf16bits(v0.z);
      a[s][3] = bf16bits(v0.w);
      a[s][4] = bf16bits(v1.x);
      a[s][5] = bf16bits(v1.y);
      a[s][6] = bf16bits(v1.z);
      a[s][7] = bf16bits(v1.w);
    }
#pragma unroll
    for (int cs = 0; cs < 8; ++cs) {
      short8 b = *(const short8*)&wt[cs * 16 + lr][ks * 32 + lq * 8];
      acc[0][cs] =
          __builtin_amdgcn_mfma_f32_16x16x32_bf16(a[0], b, acc[0][cs], 0, 0, 0);
      acc[1][cs] =
          __builtin_amdgcn_mfma_f32_16x16x32_bf16(a[1], b, acc[1][cs], 0, 0, 0);
    }
  }
#pragma unroll
  for (int s = 0; s < 2; ++s) {
#pragma unroll
    for (int cs = 0; cs < 8; ++cs) {
      int col = cs * 16 + lr;
      int r0 = rowbase + s * 16 + lq * 4;
#pragma unroll
      for (int j = 0; j < 4; ++j) {
        int r = r0 + j;
        if (r < n) y[(size_t)r * 128 + col] = bf16bits(acc[s][cs][j]);
      }
    }
  }
}

// Init per-bucket append cursors to bucket bases.
__global__ void ginit(int* __restrict__ gcur, int NC, int CAP) {
  int i = blockIdx.x * 256 + threadIdx.x;
  if (i < NC) gcur[i] = i * CAP;
}

// Block-aggregated coarse scatter into fixed-capacity bucket regions.
__global__ __launch_bounds__(256) void scatter1(const int* __restrict__ rows,
                                                const int* __restrict__ cols,
                                                const float* __restrict__ vals,
                                                int* __restrict__ gcur,
                                                int2* __restrict__ st1, int E,
                                                int NC) {
  __shared__ int lh[MAXC], gb[MAXC], lc[MAXC];
  __shared__ int rc[CHUNK];
  const int tid = threadIdx.x;
  lh[tid] = 0;
  __syncthreads();
  const int base = blockIdx.x * CHUNK;
#pragma unroll
  for (int k = 0; k < CITER; ++k) {
    int e = base + k * 256 + tid;
    int r = -1;
    if (e < E) {
      r = __builtin_nontemporal_load(rows + e);
      atomicAdd(&lh[r >> 9], 1);
    }
    rc[k * 256 + tid] = r;
  }
  __syncthreads();
  if (tid < NC) {
    int n = lh[tid];
    gb[tid] = n ? atomicAdd(&gcur[tid], n) : 0;
    lc[tid] = 0;
  }
  __syncthreads();
#pragma unroll
  for (int k = 0; k < CITER; ++k) {
    int e = base + k * 256 + tid;
    int r = rc[k * 256 + tid];
    if (r >= 0) {
      int c = r >> 9;
      int off = atomicAdd(&lc[c], 1);
      int2 o;
      o.x = ((r & 511) << 17) | __builtin_nontemporal_load(cols + e);
      o.y = __float_as_int(__builtin_nontemporal_load(vals + e));
      st1[gb[c] + off] = o;
    }
  }
}

// Refine each coarse bucket into exact rows; emit per-row {start,end}.
__global__ __launch_bounds__(512) void scatter2(const int* __restrict__ gcur,
                                                const int2* __restrict__ st1,
                                                int2* __restrict__ st2,
                                                int2* __restrict__ rowse,
                                                int CAP) {
  __shared__ int sh[512], cur[512];
  const int c = blockIdx.x, tid = threadIdx.x;
  const int a = c * CAP;
  const int b = gcur[c];  // a + count
  sh[tid] = 0;
  __syncthreads();
  for (int e = a + tid; e < b; e += 512)
    atomicAdd(&sh[(st1[e].x >> 17) & 511], 1);
  __syncthreads();
  int v = sh[tid];
  __syncthreads();
  for (int o = 1; o < 512; o <<= 1) {
    int t2 = (tid >= o) ? sh[tid - o] : 0;
    __syncthreads();
    sh[tid] += t2;
    __syncthreads();
  }
  int end = a + sh[tid];
  int start = end - v;
  cur[tid] = start;
  rowse[c * 512 + tid] = make_int2(start, end);
  __syncthreads();
  for (int e = a + tid; e < b; e += 512) {
    int2 d = st1[e];
    int r = (d.x >> 17) & 511;
    int p = atomicAdd(&cur[r], 1);
    st2[p] = make_int2(d.x & 0x1FFFF, d.y);
  }
}

// Gather-dot for one row's edge range: 8-deep (R7 operating point).
static __device__ __forceinline__ void row_dot(
    int e, int e1, const int2* __restrict__ edges,
    const unsigned short* __restrict__ src, unsigned loff, float& a0,
    float& a1) {
  for (; e + 7 < e1; e += 8) {
    int4 p0 = *(const int4*)&edges[e];
    int4 p1 = *(const int4*)&edges[e + 2];
    int4 p2 = *(const int4*)&edges[e + 4];
    int4 p3 = *(const int4*)&edges[e + 6];
    unsigned u0 = *(const unsigned*)(src + (((size_t)p0.x) << 7) + loff);
    unsigned u1 = *(const unsigned*)(src + (((size_t)p0.z) << 7) + loff);
    unsigned u2 = *(const unsigned*)(src + (((size_t)p1.x) << 7) + loff);
    unsigned u3 = *(const unsigned*)(src + (((size_t)p1.z) << 7) + loff);
    unsigned u4 = *(const unsigned*)(src + (((size_t)p2.x) << 7) + loff);
    unsigned u5 = *(const unsigned*)(src + (((size_t)p2.z) << 7) + loff);
    unsigned u6 = *(const unsigned*)(src + (((size_t)p3.x) << 7) + loff);
    unsigned u7 = *(const unsigned*)(src + (((size_t)p3.z) << 7) + loff);
    float v0 = __int_as_float(p0.y), v1 = __int_as_float(p0.w);
    float v2 = __int_as_float(p1.y), v3 = __int_as_float(p1.w);
    float v4 = __int_as_float(p2.y), v5 = __int_as_float(p2.w);
    float v6 = __int_as_float(p3.y), v7 = __int_as_float(p3.w);
    a0 += v0 * bflo(u0);
    a1 += v0 * bfhi(u0);
    a0 += v1 * bflo(u1);
    a1 += v1 * bfhi(u1);
    a0 += v2 * bflo(u2);
    a1 += v2 * bfhi(u2);
    a0 += v3 * bflo(u3);
    a1 += v3 * bfhi(u3);
    a0 += v4 * bflo(u4);
    a1 += v4 * bfhi(u4);
    a0 += v5 * bflo(u5);
    a1 += v5 * bfhi(u5);
    a0 += v6 * bflo(u6);
    a1 += v6 * bfhi(u6);
    a0 += v7 * bflo(u7);
    a1 += v7 * bfhi(u7);
  }
  for (; e < e1; ++e) {
    int2 d = edges[e];
    unsigned u = *(const unsigned*)(src + (((size_t)d.x) << 7) + loff);
    float v = __int_as_float(d.y);
    a0 += v * bflo(u);
    a1 += v * bfhi(u);
  }
}

// SPMM: one wave per row; lane owns features {2l,2l+1} (256 B/gather).
// MID: dst(bf16)=filt[row]*(A*src).  !MID: out(f32) (=/+=) A*src.
template <int MID>
__global__ __launch_bounds__(256) void spmm_w(
    const int2* __restrict__ rowse, const int2* __restrict__ edges,
    const unsigned short* __restrict__ src, unsigned short* __restrict__ dst,
    float* __restrict__ out, const float* __restrict__ filt, int N, int accm) {
  const int lane = threadIdx.x & 63, wid = threadIdx.x >> 6;
  const int row = blockIdx.x * 4 + wid;
  if (row >= N) return;
  const int2 se = rowse[row];
  float a0 = 0.f, a1 = 0.f;
  const unsigned loff = (unsigned)(lane << 1);
  row_dot(se.x, se.y, edges, src, loff, a0, a1);
  if (MID) {
    float fl = filt[row];
    a0 *= fl;
    a1 *= fl;
    unsigned o = (unsigned)bf16bits(a0) | ((unsigned)bf16bits(a1) << 16);
    *(unsigned*)(dst + ((size_t)row << 7) + loff) = o;
  } else {
    float* op = out + ((size_t)row << 7) + loff;
    float2 r;
    r.x = a0;
    r.y = a1;
    if (accm) {
      float2 c = *(const float2*)op;
      r.x += c.x;
      r.y += c.y;
    }
    *(float2*)op = r;
  }
}

// Fused out-pass over all 3 branches: out = A1*t1 + A2*t2 + A3*t3 (one write).
__global__ __launch_bounds__(256) void spmm_out3(
    const int2* __restrict__ rs1, const int2* __restrict__ rs2,
    const int2* __restrict__ rs3, const int2* __restrict__ e1,
    const int2* __restrict__ e2, const int2* __restrict__ e3,
    const unsigned short* __restrict__ t1, const unsigned short* __restrict__ t2,
    const unsigned short* __restrict__ t3, float* __restrict__ out, int N) {
  const int lane = threadIdx.x & 63, wid = threadIdx.x >> 6;
  const int row = blockIdx.x * 4 + wid;
  if (row >= N) return;
  float a0 = 0.f, a1 = 0.f;
  const unsigned loff = (unsigned)(lane << 1);
  int2 s;
  s = rs1[row];
  row_dot(s.x, s.y, e1, t1, loff, a0, a1);
  s = rs2[row];
  row_dot(s.x, s.y, e2, t2, loff, a0, a1);
  s = rs3[row];
  row_dot(s.x, s.y, e3, t3, loff, a0, a1);
  float2 r;
  r.x = a0;
  r.y = a1;
  *(float2*)(out + ((size_t)row << 7) + loff) = r;
}

extern "C" void kernel_launch(void* const* d_in, const int* in_sizes, int n_in,
                              void* d_out, int out_size, void* d_ws, size_t ws_size,
                              hipStream_t stream) {
  const float* x = (const float*)d_in[0];
  const float* w = (const float*)d_in[1];
  const float* filt[3] = {(const float*)d_in[2], (const float*)d_in[3],
                          (const float*)d_in[4]};
  const int* idx[3] = {(const int*)d_in[5], (const int*)d_in[7],
                       (const int*)d_in[9]};
  const float* val[3] = {(const float*)d_in[6], (const float*)d_in[8],
                         (const float*)d_in[10]};
  const int N = in_sizes[2];
  const int E = in_sizes[6];
  float* out = (float*)d_out;

  const int NC = (N + 511) >> 9;  // coarse buckets (512 rows each)
  // Capacity: mean + 2048 (~16 sigma for binomial bucket counts).
  const int CAP = (((E + NC - 1) / NC) + 2048 + 255) & ~255;
  const size_t NF16 = (size_t)N * 128 * sizeof(unsigned short);
  const size_t STB = (size_t)NC * CAP * 8;           // one st array
  const size_t RSB = ((size_t)(NC << 9) * 8 + 255) & ~(size_t)255;
  const size_t GCB = (MAXC * 4 + 255) & ~(size_t)255;

  // Fused layout: xW, t1..t3, st1, st2 x3, rowse x3, gcur.
  const size_t need_fused = 4 * NF16 + 4 * STB + 3 * RSB + GCB;
  const bool fused = (ws_size >= need_fused);

  char* ws = (char*)d_ws;
  const int gE = (E + CHUNK - 1) / CHUNK;
  const int gS = (N + 3) / 4;

  if (fused) {
    unsigned short* xW = (unsigned short*)ws;
    unsigned short* t[3];
    t[0] = (unsigned short*)(ws + NF16);
    t[1] = (unsigned short*)(ws + 2 * NF16);
    t[2] = (unsigned short*)(ws + 3 * NF16);
    size_t off = 4 * NF16;
    int2* st1 = (int2*)(ws + off);
    off += STB;
    int2* st2[3];
    for (int b = 0; b < 3; ++b) {
      st2[b] = (int2*)(ws + off);
      off += STB;
    }
    int2* rowse[3];
    for (int b = 0; b < 3; ++b) {
      rowse[b] = (int2*)(ws + off);
      off += RSB;
    }
    int* gcur = (int*)(ws + off);

    gemm_mfma<<<(N + 127) / 128, 256, 0, stream>>>(x, w, xW, N);
    for (int b = 0; b < 3; ++b) {
      ginit<<<(NC + 255) / 256, 256, 0, stream>>>(gcur, NC, CAP);
      scatter1<<<gE, 256, 0, stream>>>(idx[b], idx[b] + E, val[b], gcur, st1,
                                       E, NC);
      scatter2<<<NC, 512, 0, stream>>>(gcur, st1, st2[b], rowse[b], CAP);
    }
    for (int b = 0; b < 3; ++b)
      spmm_w<1><<<gS, 256, 0, stream>>>(rowse[b], st2[b], xW, t[b], nullptr,
                                        filt[b], N, 0);
    spmm_out3<<<gS, 256, 0, stream>>>(rowse[0], rowse[1], rowse[2], st2[0],
                                      st2[1], st2[2], t[0], t[1], t[2], out, N);
  } else {
    unsigned short* xW = (unsigned short*)ws;
    unsigned short* t = (unsigned short*)(ws + NF16);
    size_t off = 2 * NF16;
    int2* st1 = (int2*)(ws + off);
    off += STB;
    int2* st2 = (int2*)(ws + off);
    off += STB;
    int2* rowse = (int2*)(ws + off);
    off += RSB;
    int* gcur = (int*)(ws + off);

    gemm_mfma<<<(N + 127) / 128, 256, 0, stream>>>(x, w, xW, N);
    for (int b = 0; b < 3; ++b) {
      ginit<<<(NC + 255) / 256, 256, 0, stream>>>(gcur, NC, CAP);
      scatter1<<<gE, 256, 0, stream>>>(idx[b], idx[b] + E, val[b], gcur, st1,
                                       E, NC);
      scatter2<<<NC, 512, 0, stream>>>(gcur, st1, st2, rowse, CAP);
      spmm_w<1><<<gS, 256, 0, stream>>>(rowse, st2, xW, t, nullptr, filt[b], N,
                                        0);
      spmm_w<0><<<gS, 256, 0, stream>>>(rowse, st2, t, nullptr, out, nullptr,
                                        N, b > 0 ? 1 : 0);
    }
  }
}